// Round 1
// baseline (6211.163 us; speedup 1.0000x reference)
//
#include <hip/hip_runtime.h>
#include <hip/hip_bf16.h>

// FEDformer layer, MI355X fp32 baseline.
// B=8 T=4096 D=512 H=8 E=64 M=64 CM=4 (Dff=2048). Only lowest 64 modes survive
// the Fourier block, so we compute a 64-mode DFT/iDFT directly as small GEMMs
// and move the Wp projection into frequency space (kills the big q GEMM + FFTs).

#define T_LEN 4096
#define D_MODEL 512
#define NB 8
#define NH 8
#define NE 64
#define NM 64
#define DFF 2048
#define NROWS (NB * T_LEN)  // 32768

// ---------------- K0: basis[t][2m]=cos(2pi m t/T), [2m+1]=sin ----------------
__global__ __launch_bounds__(256) void basis_kernel(float* __restrict__ basis) {
    int idx = blockIdx.x * 256 + threadIdx.x;  // 262144 total
    int t = idx >> 6, m = idx & 63;
    int r = (t * m) & (T_LEN - 1);             // exact angle mod 2pi
    float ang = (float)r * 1.5339807878856412e-3f;  // 2*pi/4096
    float s, c;
    sincosf(ang, &s, &c);
    basis[t * 128 + 2 * m]     = c;
    basis[t * 128 + 2 * m + 1] = s;
}

// ---------------- K1: Xm[b][d][m][2] = sum_t x[b,t,d] e^{-i th} --------------
// block = (dgroup of 8, b), 512 thr = 8 waves; wave w -> d, lane -> m.
__global__ __launch_bounds__(512) void dft_kernel(const float* __restrict__ x,
                                                  const float* __restrict__ basis,
                                                  float* __restrict__ Xm) {
    int b = blockIdx.y;
    int d = blockIdx.x * 8 + (threadIdx.x >> 6);
    int m = threadIdx.x & 63;
    const float* xp = x + (size_t)b * T_LEN * D_MODEL + d;
    const float* bp = basis + 2 * m;
    float xr = 0.f, xi = 0.f;
#pragma unroll 8
    for (int t = 0; t < T_LEN; ++t) {
        float xv = xp[(size_t)t * D_MODEL];
        float2 cs = *(const float2*)(bp + t * 128);
        xr = fmaf(xv, cs.x, xr);
        xi = fmaf(xv, -cs.y, xi);
    }
    size_t o = ((size_t)(b * D_MODEL + d) * NM + m) * 2;
    Xm[o] = xr; Xm[o + 1] = xi;
}

// ---------------- K2: qm[b][c][m][2] = sum_d Xm[b][d][m] * Wp[d][c] ----------
// block = (m, b), 512 lanes = output channel c. + bp*T at m==0 (real).
__global__ __launch_bounds__(512) void proj_kernel(const float* __restrict__ Xm,
                                                   const float* __restrict__ Wp,
                                                   const float* __restrict__ bpv,
                                                   float* __restrict__ qm) {
    int m = blockIdx.x, b = blockIdx.y;
    int c = threadIdx.x;
    float qr = 0.f, qi = 0.f;
#pragma unroll 4
    for (int d = 0; d < D_MODEL; ++d) {
        float2 xv = *(const float2*)(Xm + ((size_t)(b * D_MODEL + d) * NM + m) * 2);
        float w = Wp[(size_t)d * D_MODEL + c];
        qr = fmaf(xv.x, w, qr);
        qi = fmaf(xv.y, w, qi);
    }
    if (m == 0) qr += bpv[c] * (float)T_LEN;
    size_t o = ((size_t)(b * D_MODEL + c) * NM + m) * 2;
    qm[o] = qr; qm[o + 1] = qi;
}

// ---------------- K3: om[b,h,o,m] = sum_i qm[b,h,i,m]*(wr+j wi)[h,i,o,m] -----
// writes omB[b][k][c'] with k=2m (cos coef) / 2m+1 (sin coef), irfft scaling folded.
// block = (o, h), 64 lanes = m; loops all 8 batches.
__global__ __launch_bounds__(64) void mix_kernel(const float* __restrict__ qm,
                                                 const float* __restrict__ wre,
                                                 const float* __restrict__ wim,
                                                 float* __restrict__ omB) {
    int o = blockIdx.x, h = blockIdx.y, m = threadIdx.x;
    float ar[NB], ai[NB];
#pragma unroll
    for (int b = 0; b < NB; ++b) { ar[b] = 0.f; ai[b] = 0.f; }
    for (int i = 0; i < NE; ++i) {
        size_t wo = (((size_t)(h * NE + i) * NE + o) * NM) + m;
        float wr = wre[wo], wi = wim[wo];
#pragma unroll
        for (int b = 0; b < NB; ++b) {
            float2 q = *(const float2*)(qm + ((size_t)(b * D_MODEL + h * NE + i) * NM + m) * 2);
            ar[b] = fmaf(q.x, wr, fmaf(-q.y, wi, ar[b]));
            ai[b] = fmaf(q.x, wi, fmaf(q.y, wr, ai[b]));
        }
    }
    float cm = (m == 0) ? (1.0f / T_LEN) : (2.0f / T_LEN);
    int cidx = h * NE + o;
#pragma unroll
    for (int b = 0; b < NB; ++b) {
        // attn[t] = sum_m cm*(Re om * cos + Im om * (-sin)); irfft drops Im at DC.
        omB[((size_t)b * 128 + 2 * m) * D_MODEL + cidx]     = ar[b] * cm;
        omB[((size_t)b * 128 + 2 * m + 1) * D_MODEL + cidx] = (m == 0) ? 0.f : -ai[b] * cm;
    }
}

// ---------------- K4: x' = x + basis[t][k] @ omB[k][d];  -> xw and out -------
// per b: [4096 x 128] x [128 x 512] GEMM, 64x64 tiles, 4x4 microtile.
__global__ __launch_bounds__(256) void idft_kernel(const float* __restrict__ x,
                                                   const float* __restrict__ basis,
                                                   const float* __restrict__ omB,
                                                   float* __restrict__ xw,
                                                   float* __restrict__ out) {
    __shared__ float bs[64][129];
    __shared__ float os[128][65];
    int b = blockIdx.z;
    int tt = blockIdx.y * 64;
    int dd = blockIdx.x * 64;
    int tid = threadIdx.x;
    for (int i = tid; i < 64 * 128; i += 256) {
        int r = i >> 7, k = i & 127;
        bs[r][k] = basis[(size_t)(tt + r) * 128 + k];
    }
    for (int i = tid; i < 128 * 64; i += 256) {
        int k = i >> 6, dl = i & 63;
        os[k][dl] = omB[((size_t)b * 128 + k) * D_MODEL + dd + dl];
    }
    __syncthreads();
    int tx = tid & 15, ty = tid >> 4;
    int r0 = ty * 4, c0 = tx * 4;
    float acc[4][4] = {};
#pragma unroll 4
    for (int k = 0; k < 128; ++k) {
        float a[4], bv[4];
#pragma unroll
        for (int i = 0; i < 4; ++i) a[i] = bs[r0 + i][k];
#pragma unroll
        for (int j = 0; j < 4; ++j) bv[j] = os[k][c0 + j];
#pragma unroll
        for (int i = 0; i < 4; ++i)
#pragma unroll
            for (int j = 0; j < 4; ++j) acc[i][j] = fmaf(a[i], bv[j], acc[i][j]);
    }
#pragma unroll
    for (int i = 0; i < 4; ++i) {
        size_t off = ((size_t)b * T_LEN + tt + r0 + i) * D_MODEL + dd + c0;
        float4 xv = *(const float4*)(x + off);
        float4 o4;
        o4.x = xv.x + acc[i][0]; o4.y = xv.y + acc[i][1];
        o4.z = xv.z + acc[i][2]; o4.w = xv.w + acc[i][3];
        *(float4*)(xw + off) = o4;
        *(float4*)(out + off) = o4;
    }
}

// ---------------- K5: y1 = relu(x' @ W1^T) for column chunk [co, co+CH) ------
// 128x128 tile, BK=32, 8x8 microtile, 256 threads.
__global__ __launch_bounds__(256) void ffn1_kernel(const float* __restrict__ xp,
                                                   const float* __restrict__ W1,
                                                   float* __restrict__ y1,
                                                   int co, int CH) {
    __shared__ float as[128][36];
    __shared__ float bs[128][36];
    int rr = blockIdx.y * 128;
    int cc = co + blockIdx.x * 128;
    int tid = threadIdx.x;
    int tx = tid & 15, ty = tid >> 4;
    float acc[8][8] = {};
    for (int kk = 0; kk < D_MODEL; kk += 32) {
#pragma unroll
        for (int l = 0; l < 4; ++l) {
            int f = (tid + l * 256) * 4;
            int r = f >> 5, k = f & 31;
            *(float4*)&as[r][k] = *(const float4*)(xp + (size_t)(rr + r) * D_MODEL + kk + k);
            *(float4*)&bs[r][k] = *(const float4*)(W1 + (size_t)(cc + r) * D_MODEL + kk + k);
        }
        __syncthreads();
#pragma unroll
        for (int k4 = 0; k4 < 32; k4 += 4) {
            float4 a[8], bb[8];
#pragma unroll
            for (int i = 0; i < 8; ++i) a[i] = *(const float4*)&as[ty * 8 + i][k4];
#pragma unroll
            for (int j = 0; j < 8; ++j) bb[j] = *(const float4*)&bs[tx * 8 + j][k4];
#pragma unroll
            for (int i = 0; i < 8; ++i)
#pragma unroll
                for (int j = 0; j < 8; ++j) {
                    acc[i][j] = fmaf(a[i].x, bb[j].x, acc[i][j]);
                    acc[i][j] = fmaf(a[i].y, bb[j].y, acc[i][j]);
                    acc[i][j] = fmaf(a[i].z, bb[j].z, acc[i][j]);
                    acc[i][j] = fmaf(a[i].w, bb[j].w, acc[i][j]);
                }
        }
        __syncthreads();
    }
#pragma unroll
    for (int i = 0; i < 8; ++i) {
        size_t ro = (size_t)(rr + ty * 8 + i) * CH + (cc - co) + tx * 8;
#pragma unroll
        for (int j4 = 0; j4 < 8; j4 += 4) {
            float4 v;
            v.x = fmaxf(acc[i][j4 + 0], 0.f);
            v.y = fmaxf(acc[i][j4 + 1], 0.f);
            v.z = fmaxf(acc[i][j4 + 2], 0.f);
            v.w = fmaxf(acc[i][j4 + 3], 0.f);
            *(float4*)(y1 + ro + j4) = v;
        }
    }
}

// ---------------- K6: out += y1 @ W2^T (chunk of K) --------------------------
__global__ __launch_bounds__(256) void ffn2_kernel(const float* __restrict__ y1,
                                                   const float* __restrict__ W2,
                                                   float* __restrict__ out,
                                                   int co, int CH) {
    __shared__ float as[128][36];
    __shared__ float bs[128][36];
    int rr = blockIdx.y * 128;
    int dd = blockIdx.x * 128;
    int tid = threadIdx.x;
    int tx = tid & 15, ty = tid >> 4;
    float acc[8][8] = {};
    for (int kk = 0; kk < CH; kk += 32) {
#pragma unroll
        for (int l = 0; l < 4; ++l) {
            int f = (tid + l * 256) * 4;
            int r = f >> 5, k = f & 31;
            *(float4*)&as[r][k] = *(const float4*)(y1 + (size_t)(rr + r) * CH + kk + k);
            *(float4*)&bs[r][k] = *(const float4*)(W2 + (size_t)(dd + r) * DFF + co + kk + k);
        }
        __syncthreads();
#pragma unroll
        for (int k4 = 0; k4 < 32; k4 += 4) {
            float4 a[8], bb[8];
#pragma unroll
            for (int i = 0; i < 8; ++i) a[i] = *(const float4*)&as[ty * 8 + i][k4];
#pragma unroll
            for (int j = 0; j < 8; ++j) bb[j] = *(const float4*)&bs[tx * 8 + j][k4];
#pragma unroll
            for (int i = 0; i < 8; ++i)
#pragma unroll
                for (int j = 0; j < 8; ++j) {
                    acc[i][j] = fmaf(a[i].x, bb[j].x, acc[i][j]);
                    acc[i][j] = fmaf(a[i].y, bb[j].y, acc[i][j]);
                    acc[i][j] = fmaf(a[i].z, bb[j].z, acc[i][j]);
                    acc[i][j] = fmaf(a[i].w, bb[j].w, acc[i][j]);
                }
        }
        __syncthreads();
    }
#pragma unroll
    for (int i = 0; i < 8; ++i) {
        size_t off = (size_t)(rr + ty * 8 + i) * D_MODEL + dd + tx * 8;
#pragma unroll
        for (int j4 = 0; j4 < 8; j4 += 4) {
            float4 prev = *(const float4*)(out + off + j4);
            float4 v;
            v.x = prev.x + acc[i][j4 + 0];
            v.y = prev.y + acc[i][j4 + 1];
            v.z = prev.z + acc[i][j4 + 2];
            v.w = prev.w + acc[i][j4 + 3];
            *(float4*)(out + off + j4) = v;
        }
    }
}

extern "C" void kernel_launch(void* const* d_in, const int* in_sizes, int n_in,
                              void* d_out, int out_size, void* d_ws, size_t ws_size,
                              hipStream_t stream) {
    const float* x   = (const float*)d_in[0];
    const float* Wp  = (const float*)d_in[1];
    const float* bpv = (const float*)d_in[2];
    const float* wre = (const float*)d_in[3];
    const float* wim = (const float*)d_in[4];
    const float* W1  = (const float*)d_in[5];
    const float* W2  = (const float*)d_in[6];
    float* out = (float*)d_out;

    char* ws = (char*)d_ws;
    const size_t MB = (size_t)1 << 20;
    float* basis = (float*)(ws + 0 * MB);   // 2 MB
    float* Xm    = (float*)(ws + 2 * MB);   // 2 MB
    float* qm    = (float*)(ws + 4 * MB);   // 2 MB
    float* omB   = (float*)(ws + 6 * MB);   // 2 MB
    float* xw    = (float*)(ws + 8 * MB);   // 64 MB  (x' = x + attn)
    float* y1    = (float*)(ws + 72 * MB);  // up to 256 MB

    // pick the largest FFN column chunk that fits the workspace
    size_t avail = (ws_size > 72 * MB) ? ws_size - 72 * MB : 0;
    int CH = 2048;
    while (CH > 128 && (size_t)NROWS * CH * sizeof(float) > avail) CH >>= 1;

    basis_kernel<<<1024, 256, 0, stream>>>(basis);
    dft_kernel<<<dim3(64, 8), 512, 0, stream>>>(x, basis, Xm);
    proj_kernel<<<dim3(64, 8), 512, 0, stream>>>(Xm, Wp, bpv, qm);
    mix_kernel<<<dim3(64, 8), 64, 0, stream>>>(qm, wre, wim, omB);
    idft_kernel<<<dim3(8, 64, 8), 256, 0, stream>>>(x, basis, omB, xw, out);
    for (int co = 0; co < DFF; co += CH) {
        ffn1_kernel<<<dim3(CH / 128, NROWS / 128), 256, 0, stream>>>(xw, W1, y1, co, CH);
        ffn2_kernel<<<dim3(D_MODEL / 128, NROWS / 128), 256, 0, stream>>>(y1, W2, out, co, CH);
    }
}

// Round 4
// 1436.314 us; speedup vs baseline: 4.3244x; 4.3244x over previous
//
#include <hip/hip_runtime.h>
#include <hip/hip_bf16.h>

// FEDformer layer, MI355X. Round 2 kernel, third submission (rounds 2/3 never
// ran: GPU acquisition timeout, then container bring-up failure).
// FFN on matrix cores via split-bf16 (hi/lo) 3-term GEMM.
// B=8 T=4096 D=512 H=8 E=64 M=64 CM=4 (Dff=2048). Only lowest 64 modes survive
// the Fourier block -> 64-mode DFT/iDFT as small GEMMs, Wp projection done in
// frequency space.

#define T_LEN 4096
#define D_MODEL 512
#define NB 8
#define NH 8
#define NE 64
#define NM 64
#define DFF 2048
#define NROWS (NB * T_LEN)  // 32768

typedef __attribute__((ext_vector_type(8))) short bf16x8;
typedef __attribute__((ext_vector_type(4))) float f32x4;

__device__ inline ushort f2bf_rne(float f) {
    unsigned u = __float_as_uint(f);
    unsigned r = u + 0x7FFFu + ((u >> 16) & 1u);
    return (ushort)(r >> 16);
}
__device__ inline float bf2f(ushort h) { return __uint_as_float(((unsigned)h) << 16); }
__device__ inline void split_bf16(float v, ushort& h, ushort& l) {
    h = f2bf_rne(v);
    l = f2bf_rne(v - bf2f(h));
}

#define GLOAD16(gp, lp)                                                            \
    __builtin_amdgcn_global_load_lds(                                              \
        (const __attribute__((address_space(1))) void*)(gp),                       \
        (__attribute__((address_space(3))) void*)(lp), 16, 0, 0)

// ---------------- K0: basis[t][2m]=cos(2pi m t/T), [2m+1]=sin ----------------
__global__ __launch_bounds__(256) void basis_kernel(float* __restrict__ basis) {
    int idx = blockIdx.x * 256 + threadIdx.x;  // 262144 total
    int t = idx >> 6, m = idx & 63;
    int r = (t * m) & (T_LEN - 1);
    float ang = (float)r * 1.5339807878856412e-3f;  // 2*pi/4096
    float s, c;
    sincosf(ang, &s, &c);
    basis[t * 128 + 2 * m]     = c;
    basis[t * 128 + 2 * m + 1] = s;
}

// ---------------- K0b: fp32 -> (hi,lo) bf16 decomposition --------------------
__global__ __launch_bounds__(256) void decomp_kernel(const float* __restrict__ in,
                                                     ushort* __restrict__ hi,
                                                     ushort* __restrict__ lo, int n4) {
    int i = blockIdx.x * 256 + threadIdx.x;
    if (i >= n4) return;
    float4 v = ((const float4*)in)[i];
    ushort4 h, l;
    split_bf16(v.x, h.x, l.x);
    split_bf16(v.y, h.y, l.y);
    split_bf16(v.z, h.z, l.z);
    split_bf16(v.w, h.w, l.w);
    ((ushort4*)hi)[i] = h;
    ((ushort4*)lo)[i] = l;
}

// ---------------- K1: Xm[b][d][m][2] = sum_t x[b,t,d] e^{-i th} --------------
__global__ __launch_bounds__(512) void dft_kernel(const float* __restrict__ x,
                                                  const float* __restrict__ basis,
                                                  float* __restrict__ Xm) {
    int b = blockIdx.y;
    int d = blockIdx.x * 8 + (threadIdx.x >> 6);
    int m = threadIdx.x & 63;
    const float* xp = x + (size_t)b * T_LEN * D_MODEL + d;
    const float* bp = basis + 2 * m;
    float xr = 0.f, xi = 0.f;
#pragma unroll 8
    for (int t = 0; t < T_LEN; ++t) {
        float xv = xp[(size_t)t * D_MODEL];
        float2 cs = *(const float2*)(bp + t * 128);
        xr = fmaf(xv, cs.x, xr);
        xi = fmaf(xv, -cs.y, xi);
    }
    size_t o = ((size_t)(b * D_MODEL + d) * NM + m) * 2;
    Xm[o] = xr; Xm[o + 1] = xi;
}

// ---------------- K2: qm[b][c][m][2] = sum_d Xm[b][d][m] * Wp[d][c] ----------
__global__ __launch_bounds__(512) void proj_kernel(const float* __restrict__ Xm,
                                                   const float* __restrict__ Wp,
                                                   const float* __restrict__ bpv,
                                                   float* __restrict__ qm) {
    int m = blockIdx.x, b = blockIdx.y;
    int c = threadIdx.x;
    float qr = 0.f, qi = 0.f;
#pragma unroll 4
    for (int d = 0; d < D_MODEL; ++d) {
        float2 xv = *(const float2*)(Xm + ((size_t)(b * D_MODEL + d) * NM + m) * 2);
        float w = Wp[(size_t)d * D_MODEL + c];
        qr = fmaf(xv.x, w, qr);
        qi = fmaf(xv.y, w, qi);
    }
    if (m == 0) qr += bpv[c] * (float)T_LEN;
    size_t o = ((size_t)(b * D_MODEL + c) * NM + m) * 2;
    qm[o] = qr; qm[o + 1] = qi;
}

// ---------------- K3: per-mode complex mixing; irfft scaling folded ----------
__global__ __launch_bounds__(64) void mix_kernel(const float* __restrict__ qm,
                                                 const float* __restrict__ wre,
                                                 const float* __restrict__ wim,
                                                 float* __restrict__ omB) {
    int o = blockIdx.x, h = blockIdx.y, m = threadIdx.x;
    float ar[NB], ai[NB];
#pragma unroll
    for (int b = 0; b < NB; ++b) { ar[b] = 0.f; ai[b] = 0.f; }
    for (int i = 0; i < NE; ++i) {
        size_t wo = (((size_t)(h * NE + i) * NE + o) * NM) + m;
        float wr = wre[wo], wi = wim[wo];
#pragma unroll
        for (int b = 0; b < NB; ++b) {
            float2 q = *(const float2*)(qm + ((size_t)(b * D_MODEL + h * NE + i) * NM + m) * 2);
            ar[b] = fmaf(q.x, wr, fmaf(-q.y, wi, ar[b]));
            ai[b] = fmaf(q.x, wi, fmaf(q.y, wr, ai[b]));
        }
    }
    float cm = (m == 0) ? (1.0f / T_LEN) : (2.0f / T_LEN);
    int cidx = h * NE + o;
#pragma unroll
    for (int b = 0; b < NB; ++b) {
        omB[((size_t)b * 128 + 2 * m) * D_MODEL + cidx]     = ar[b] * cm;
        omB[((size_t)b * 128 + 2 * m + 1) * D_MODEL + cidx] = (m == 0) ? 0.f : -ai[b] * cm;
    }
}

// ---------------- K4: x' = x + basis @ omB -> out (fp32) + xh hi/lo (bf16) ---
__global__ __launch_bounds__(256) void idft_kernel(const float* __restrict__ x,
                                                   const float* __restrict__ basis,
                                                   const float* __restrict__ omB,
                                                   ushort* __restrict__ xh_hi,
                                                   ushort* __restrict__ xh_lo,
                                                   float* __restrict__ out) {
    __shared__ float bs[64][129];
    __shared__ float os[128][65];
    int b = blockIdx.z;
    int tt = blockIdx.y * 64;
    int dd = blockIdx.x * 64;
    int tid = threadIdx.x;
    for (int i = tid; i < 64 * 128; i += 256) {
        int r = i >> 7, k = i & 127;
        bs[r][k] = basis[(size_t)(tt + r) * 128 + k];
    }
    for (int i = tid; i < 128 * 64; i += 256) {
        int k = i >> 6, dl = i & 63;
        os[k][dl] = omB[((size_t)b * 128 + k) * D_MODEL + dd + dl];
    }
    __syncthreads();
    int tx = tid & 15, ty = tid >> 4;
    int r0 = ty * 4, c0 = tx * 4;
    float acc[4][4] = {};
#pragma unroll 4
    for (int k = 0; k < 128; ++k) {
        float a[4], bv[4];
#pragma unroll
        for (int i = 0; i < 4; ++i) a[i] = bs[r0 + i][k];
#pragma unroll
        for (int j = 0; j < 4; ++j) bv[j] = os[k][c0 + j];
#pragma unroll
        for (int i = 0; i < 4; ++i)
#pragma unroll
            for (int j = 0; j < 4; ++j) acc[i][j] = fmaf(a[i], bv[j], acc[i][j]);
    }
#pragma unroll
    for (int i = 0; i < 4; ++i) {
        size_t off = ((size_t)b * T_LEN + tt + r0 + i) * D_MODEL + dd + c0;
        float4 xv = *(const float4*)(x + off);
        float4 o4;
        o4.x = xv.x + acc[i][0]; o4.y = xv.y + acc[i][1];
        o4.z = xv.z + acc[i][2]; o4.w = xv.w + acc[i][3];
        *(float4*)(out + off) = o4;
        ushort4 hv, lv;
        split_bf16(o4.x, hv.x, lv.x);
        split_bf16(o4.y, hv.y, lv.y);
        split_bf16(o4.z, hv.z, lv.z);
        split_bf16(o4.w, hv.w, lv.w);
        *(ushort4*)(xh_hi + off) = hv;
        *(ushort4*)(xh_lo + off) = lv;
    }
}

// ============== MFMA FFN: 128x128 tile, BK=32, 4 waves, 4x4 frags ============
// C[r][c] = sum_k A[r][k]*B[c][k]  (both operands K-major, split hi/lo bf16)
// 3-term split: Ah*Bh + Al*Bh + Ah*Bl  (Al*Bl ~ 2^-18, dropped)

// ---------------- K5: y1 = relu(x' @ W1^T) -> hi/lo bf16 ---------------------
__global__ __launch_bounds__(256) void ffn1_mfma(const ushort* __restrict__ Ag_h,
                                                 const ushort* __restrict__ Ag_l,
                                                 const ushort* __restrict__ Bg_h,
                                                 const ushort* __restrict__ Bg_l,
                                                 ushort* __restrict__ Yh,
                                                 ushort* __restrict__ Yl,
                                                 int co, int CH) {
    __shared__ ushort Ah[128][32], Al[128][32], Bh[128][32], Bl[128][32];
    int rr = blockIdx.y * 128;
    int ccl = blockIdx.x * 128;   // local col within chunk
    int cc = co + ccl;            // global col (row of W1)
    int tid = threadIdx.x;
    int lane = tid & 63, w = tid >> 6;
    int wr = (w >> 1) * 64, wc = (w & 1) * 64;
    f32x4 acc[4][4] = {};
    int c0 = w * 2;                      // this wave's 16-row chunk pair
    int srow = c0 * 16 + (lane >> 2);    // staging row (lane-linear)
    int koff = (lane & 3) * 8;           // staging k element offset

    for (int kk = 0; kk < D_MODEL; kk += 32) {
        GLOAD16(Ag_h + (size_t)(rr + srow) * D_MODEL + kk + koff, &Ah[c0 * 16][0]);
        GLOAD16(Ag_h + (size_t)(rr + srow + 16) * D_MODEL + kk + koff, &Ah[c0 * 16 + 16][0]);
        GLOAD16(Ag_l + (size_t)(rr + srow) * D_MODEL + kk + koff, &Al[c0 * 16][0]);
        GLOAD16(Ag_l + (size_t)(rr + srow + 16) * D_MODEL + kk + koff, &Al[c0 * 16 + 16][0]);
        GLOAD16(Bg_h + (size_t)(cc + srow) * D_MODEL + kk + koff, &Bh[c0 * 16][0]);
        GLOAD16(Bg_h + (size_t)(cc + srow + 16) * D_MODEL + kk + koff, &Bh[c0 * 16 + 16][0]);
        GLOAD16(Bg_l + (size_t)(cc + srow) * D_MODEL + kk + koff, &Bl[c0 * 16][0]);
        GLOAD16(Bg_l + (size_t)(cc + srow + 16) * D_MODEL + kk + koff, &Bl[c0 * 16 + 16][0]);
        __syncthreads();
        int arow = wr + (lane & 15);
        int kq = (lane >> 4) * 8;
        bf16x8 afh[4], afl[4];
#pragma unroll
        for (int i = 0; i < 4; ++i) {
            afh[i] = *(const bf16x8*)&Ah[arow + i * 16][kq];
            afl[i] = *(const bf16x8*)&Al[arow + i * 16][kq];
        }
#pragma unroll
        for (int j = 0; j < 4; ++j) {
            int brow = wc + j * 16 + (lane & 15);
            bf16x8 bfh = *(const bf16x8*)&Bh[brow][kq];
            bf16x8 bfl = *(const bf16x8*)&Bl[brow][kq];
#pragma unroll
            for (int i = 0; i < 4; ++i) {
                acc[i][j] = __builtin_amdgcn_mfma_f32_16x16x32_bf16(afh[i], bfh, acc[i][j], 0, 0, 0);
                acc[i][j] = __builtin_amdgcn_mfma_f32_16x16x32_bf16(afl[i], bfh, acc[i][j], 0, 0, 0);
                acc[i][j] = __builtin_amdgcn_mfma_f32_16x16x32_bf16(afh[i], bfl, acc[i][j], 0, 0, 0);
            }
        }
        __syncthreads();
    }
#pragma unroll
    for (int i = 0; i < 4; ++i) {
        int row = rr + wr + i * 16 + (lane >> 4) * 4;
#pragma unroll
        for (int j = 0; j < 4; ++j) {
            int col = ccl + wc + j * 16 + (lane & 15);
#pragma unroll
            for (int q = 0; q < 4; ++q) {
                float v = fmaxf(acc[i][j][q], 0.f);
                ushort h, l;
                split_bf16(v, h, l);
                size_t o = (size_t)(row + q) * CH + col;
                Yh[o] = h;
                Yl[o] = l;
            }
        }
    }
}

// ---------------- K6: out += y1 @ W2^T (K-chunk [co, co+CH)) -----------------
__global__ __launch_bounds__(256) void ffn2_mfma(const ushort* __restrict__ Ag_h,
                                                 const ushort* __restrict__ Ag_l,
                                                 const ushort* __restrict__ Bg_h,
                                                 const ushort* __restrict__ Bg_l,
                                                 float* __restrict__ out,
                                                 int co, int CH) {
    __shared__ ushort Ah[128][32], Al[128][32], Bh[128][32], Bl[128][32];
    int rr = blockIdx.y * 128;
    int dd = blockIdx.x * 128;
    int tid = threadIdx.x;
    int lane = tid & 63, w = tid >> 6;
    int wr = (w >> 1) * 64, wc = (w & 1) * 64;
    f32x4 acc[4][4] = {};
    int c0 = w * 2;
    int srow = c0 * 16 + (lane >> 2);
    int koff = (lane & 3) * 8;

    for (int kk = 0; kk < CH; kk += 32) {
        GLOAD16(Ag_h + (size_t)(rr + srow) * CH + kk + koff, &Ah[c0 * 16][0]);
        GLOAD16(Ag_h + (size_t)(rr + srow + 16) * CH + kk + koff, &Ah[c0 * 16 + 16][0]);
        GLOAD16(Ag_l + (size_t)(rr + srow) * CH + kk + koff, &Al[c0 * 16][0]);
        GLOAD16(Ag_l + (size_t)(rr + srow + 16) * CH + kk + koff, &Al[c0 * 16 + 16][0]);
        GLOAD16(Bg_h + (size_t)(dd + srow) * DFF + co + kk + koff, &Bh[c0 * 16][0]);
        GLOAD16(Bg_h + (size_t)(dd + srow + 16) * DFF + co + kk + koff, &Bh[c0 * 16 + 16][0]);
        GLOAD16(Bg_l + (size_t)(dd + srow) * DFF + co + kk + koff, &Bl[c0 * 16][0]);
        GLOAD16(Bg_l + (size_t)(dd + srow + 16) * DFF + co + kk + koff, &Bl[c0 * 16 + 16][0]);
        __syncthreads();
        int arow = wr + (lane & 15);
        int kq = (lane >> 4) * 8;
        bf16x8 afh[4], afl[4];
#pragma unroll
        for (int i = 0; i < 4; ++i) {
            afh[i] = *(const bf16x8*)&Ah[arow + i * 16][kq];
            afl[i] = *(const bf16x8*)&Al[arow + i * 16][kq];
        }
#pragma unroll
        for (int j = 0; j < 4; ++j) {
            int brow = wc + j * 16 + (lane & 15);
            bf16x8 bfh = *(const bf16x8*)&Bh[brow][kq];
            bf16x8 bfl = *(const bf16x8*)&Bl[brow][kq];
#pragma unroll
            for (int i = 0; i < 4; ++i) {
                acc[i][j] = __builtin_amdgcn_mfma_f32_16x16x32_bf16(afh[i], bfh, acc[i][j], 0, 0, 0);
                acc[i][j] = __builtin_amdgcn_mfma_f32_16x16x32_bf16(afl[i], bfh, acc[i][j], 0, 0, 0);
                acc[i][j] = __builtin_amdgcn_mfma_f32_16x16x32_bf16(afh[i], bfl, acc[i][j], 0, 0, 0);
            }
        }
        __syncthreads();
    }
#pragma unroll
    for (int i = 0; i < 4; ++i) {
        int row = rr + wr + i * 16 + (lane >> 4) * 4;
#pragma unroll
        for (int j = 0; j < 4; ++j) {
            int col = dd + wc + j * 16 + (lane & 15);
#pragma unroll
            for (int q = 0; q < 4; ++q) {
                size_t o = (size_t)(row + q) * D_MODEL + col;
                out[o] += acc[i][j][q];
            }
        }
    }
}

extern "C" void kernel_launch(void* const* d_in, const int* in_sizes, int n_in,
                              void* d_out, int out_size, void* d_ws, size_t ws_size,
                              hipStream_t stream) {
    const float* x   = (const float*)d_in[0];
    const float* Wp  = (const float*)d_in[1];
    const float* bpv = (const float*)d_in[2];
    const float* wre = (const float*)d_in[3];
    const float* wim = (const float*)d_in[4];
    const float* W1  = (const float*)d_in[5];
    const float* W2  = (const float*)d_in[6];
    float* out = (float*)d_out;

    char* ws = (char*)d_ws;
    const size_t MB = (size_t)1 << 20;
    float*  basis = (float*)(ws + 0 * MB);    // 2 MB
    float*  Xm    = (float*)(ws + 2 * MB);    // 2 MB
    float*  qm    = (float*)(ws + 4 * MB);    // 2 MB
    float*  omB   = (float*)(ws + 6 * MB);    // 2 MB
    ushort* w1h   = (ushort*)(ws + 8 * MB);   // 2 MB
    ushort* w1l   = (ushort*)(ws + 10 * MB);  // 2 MB
    ushort* w2h   = (ushort*)(ws + 12 * MB);  // 2 MB
    ushort* w2l   = (ushort*)(ws + 14 * MB);  // 2 MB
    ushort* xh_hi = (ushort*)(ws + 16 * MB);  // 32 MB
    ushort* xh_lo = (ushort*)(ws + 48 * MB);  // 32 MB
    char*   y1b   = ws + 80 * MB;             // y1 hi/lo chunk buffers

    // largest FFN column chunk whose hi/lo y1 buffers fit the workspace
    size_t avail = (ws_size > 80 * MB) ? ws_size - 80 * MB : 0;
    int CH = 2048;
    while (CH > 128 && (size_t)NROWS * CH * 2 * sizeof(ushort) > avail) CH >>= 1;
    ushort* y1h = (ushort*)y1b;
    ushort* y1l = (ushort*)(y1b + (size_t)NROWS * CH * sizeof(ushort));

    basis_kernel<<<1024, 256, 0, stream>>>(basis);
    decomp_kernel<<<1024, 256, 0, stream>>>(W1, w1h, w1l, DFF * D_MODEL / 4);
    decomp_kernel<<<1024, 256, 0, stream>>>(W2, w2h, w2l, DFF * D_MODEL / 4);
    dft_kernel<<<dim3(64, 8), 512, 0, stream>>>(x, basis, Xm);
    proj_kernel<<<dim3(64, 8), 512, 0, stream>>>(Xm, Wp, bpv, qm);
    mix_kernel<<<dim3(64, 8), 64, 0, stream>>>(qm, wre, wim, omB);
    idft_kernel<<<dim3(8, 64, 8), 256, 0, stream>>>(x, basis, omB, xh_hi, xh_lo, out);
    for (int co = 0; co < DFF; co += CH) {
        ffn1_mfma<<<dim3(CH / 128, NROWS / 128), 256, 0, stream>>>(
            xh_hi, xh_lo, w1h, w1l, y1h, y1l, co, CH);
        ffn2_mfma<<<dim3(D_MODEL / 128, NROWS / 128), 256, 0, stream>>>(
            y1h, y1l, w2h, w2l, out, co, CH);
    }
}

// Round 6
// 869.791 us; speedup vs baseline: 7.1410x; 1.6513x over previous
//
#include <hip/hip_runtime.h>
#include <hip/hip_bf16.h>

// FEDformer layer, MI355X. Round 5 kernel, second submission (round-5 bench
// died in container bring-up; kernel never ran). DFT rewritten as LDS-tiled
// fp32 GEMM (was latency-bound broadcast-load column walk: 675us, 8% VALU).
// FFN stays on matrix cores via split-bf16 (hi/lo) 3-term GEMM (round-4, passed).
// B=8 T=4096 D=512 H=8 E=64 M=64 CM=4 (Dff=2048). Only lowest 64 modes survive
// the Fourier block -> 64-mode DFT/iDFT as small GEMMs, Wp projection done in
// frequency space.

#define T_LEN 4096
#define D_MODEL 512
#define NB 8
#define NH 8
#define NE 64
#define NM 64
#define DFF 2048
#define NROWS (NB * T_LEN)  // 32768
#define NK 128              // 64 modes x (cos,sin)
#define TSPLIT 8
#define TCH (T_LEN / TSPLIT)  // 512

typedef __attribute__((ext_vector_type(8))) short bf16x8;
typedef __attribute__((ext_vector_type(4))) float f32x4;

__device__ inline ushort f2bf_rne(float f) {
    unsigned u = __float_as_uint(f);
    unsigned r = u + 0x7FFFu + ((u >> 16) & 1u);
    return (ushort)(r >> 16);
}
__device__ inline float bf2f(ushort h) { return __uint_as_float(((unsigned)h) << 16); }
__device__ inline void split_bf16(float v, ushort& h, ushort& l) {
    h = f2bf_rne(v);
    l = f2bf_rne(v - bf2f(h));
}

#define GLOAD16(gp, lp)                                                            \
    __builtin_amdgcn_global_load_lds(                                              \
        (const __attribute__((address_space(1))) void*)(gp),                       \
        (__attribute__((address_space(3))) void*)(lp), 16, 0, 0)

// ---------------- K0: basis[t][2m]=cos(2pi m t/T), [2m+1]=sin ----------------
__global__ __launch_bounds__(256) void basis_kernel(float* __restrict__ basis) {
    int idx = blockIdx.x * 256 + threadIdx.x;  // 262144 total
    int t = idx >> 6, m = idx & 63;
    int r = (t * m) & (T_LEN - 1);
    float ang = (float)r * 1.5339807878856412e-3f;  // 2*pi/4096
    float s, c;
    sincosf(ang, &s, &c);
    basis[t * 128 + 2 * m]     = c;
    basis[t * 128 + 2 * m + 1] = s;
}

// ---------------- K0b: fp32 -> (hi,lo) bf16 decomposition --------------------
__global__ __launch_bounds__(256) void decomp_kernel(const float* __restrict__ in,
                                                     ushort* __restrict__ hi,
                                                     ushort* __restrict__ lo, int n4) {
    int i = blockIdx.x * 256 + threadIdx.x;
    if (i >= n4) return;
    float4 v = ((const float4*)in)[i];
    ushort4 h, l;
    split_bf16(v.x, h.x, l.x);
    split_bf16(v.y, h.y, l.y);
    split_bf16(v.z, h.z, l.z);
    split_bf16(v.w, h.w, l.w);
    ((ushort4*)hi)[i] = h;
    ((ushort4*)lo)[i] = l;
}

// ---------------- K1: DFT as tiled GEMM: pp[tc][b][d][k] partial sums --------
// P[d][k] = sum_t x[b][t][d] * basis[t][k].  Block: 64-d-tile x 128-k, one
// t-chunk of 512.  xs loads coalesced (row-major 64-float segments).
__global__ __launch_bounds__(256) void dft2_kernel(const float* __restrict__ x,
                                                   const float* __restrict__ basis,
                                                   float* __restrict__ pp) {
    __shared__ float xs[64][68];   // [t][d] +4 pad
    __shared__ float bs[64][132];  // [t][k] +4 pad
    int d0 = blockIdx.x * 64;
    int b  = blockIdx.y;
    int tc = blockIdx.z;
    int t0 = tc * TCH;
    int tid = threadIdx.x;
    int tx = tid & 15, ty = tid >> 4;
    float4 acc0[4] = {};  // k = tx*4 + c
    float4 acc1[4] = {};  // k = 64 + tx*4 + c

    for (int tt = 0; tt < TCH; tt += 64) {
        const float* xrow = x + ((size_t)b * T_LEN + t0 + tt) * D_MODEL + d0;
#pragma unroll
        for (int l = 0; l < 4; ++l) {
            int f = (tid + l * 256) * 4;
            int r = f >> 6, c = f & 63;
            *(float4*)&xs[r][c] = *(const float4*)(xrow + (size_t)r * D_MODEL + c);
        }
        const float* brow = basis + (size_t)(t0 + tt) * NK;
#pragma unroll
        for (int l = 0; l < 8; ++l) {
            int f = (tid + l * 256) * 4;
            int r = f >> 7, c = f & 127;
            *(float4*)&bs[r][c] = *(const float4*)(brow + (size_t)r * NK + c);
        }
        __syncthreads();
#pragma unroll 4
        for (int t = 0; t < 64; ++t) {
            float4 xv = *(const float4*)&xs[t][ty * 4];
            float4 b0 = *(const float4*)&bs[t][tx * 4];
            float4 b1 = *(const float4*)&bs[t][tx * 4 + 64];
            float xa[4] = {xv.x, xv.y, xv.z, xv.w};
#pragma unroll
            for (int di = 0; di < 4; ++di) {
                acc0[di].x = fmaf(xa[di], b0.x, acc0[di].x);
                acc0[di].y = fmaf(xa[di], b0.y, acc0[di].y);
                acc0[di].z = fmaf(xa[di], b0.z, acc0[di].z);
                acc0[di].w = fmaf(xa[di], b0.w, acc0[di].w);
                acc1[di].x = fmaf(xa[di], b1.x, acc1[di].x);
                acc1[di].y = fmaf(xa[di], b1.y, acc1[di].y);
                acc1[di].z = fmaf(xa[di], b1.z, acc1[di].z);
                acc1[di].w = fmaf(xa[di], b1.w, acc1[di].w);
            }
        }
        __syncthreads();
    }
#pragma unroll
    for (int di = 0; di < 4; ++di) {
        int d = d0 + ty * 4 + di;
        size_t base = (((size_t)tc * NB + b) * D_MODEL + d) * NK;
        *(float4*)(pp + base + tx * 4)      = acc0[di];
        *(float4*)(pp + base + 64 + tx * 4) = acc1[di];
    }
}

// ---------------- K1b: reduce t-chunks, apply -sin sign ----------------------
// Xm[b][d][2m]=sum(cos part), Xm[b][d][2m+1]=-sum(sin part)
__global__ __launch_bounds__(256) void dft_reduce_kernel(const float* __restrict__ pp,
                                                         float* __restrict__ Xm) {
    int idx = blockIdx.x * 256 + threadIdx.x;  // 8*512*128 = 524288
    const size_t stride = (size_t)NB * D_MODEL * NK;
    float s = 0.f;
#pragma unroll
    for (int tc = 0; tc < TSPLIT; ++tc) s += pp[(size_t)tc * stride + idx];
    Xm[idx] = (idx & 1) ? -s : s;
}

// ---------------- K2: qm[b][c][m][2] = sum_d Xm[b][d][m] * Wp[d][c] ----------
__global__ __launch_bounds__(512) void proj_kernel(const float* __restrict__ Xm,
                                                   const float* __restrict__ Wp,
                                                   const float* __restrict__ bpv,
                                                   float* __restrict__ qm) {
    int m = blockIdx.x, b = blockIdx.y;
    int c = threadIdx.x;
    float qr = 0.f, qi = 0.f;
#pragma unroll 4
    for (int d = 0; d < D_MODEL; ++d) {
        float2 xv = *(const float2*)(Xm + ((size_t)(b * D_MODEL + d) * NM + m) * 2);
        float w = Wp[(size_t)d * D_MODEL + c];
        qr = fmaf(xv.x, w, qr);
        qi = fmaf(xv.y, w, qi);
    }
    if (m == 0) qr += bpv[c] * (float)T_LEN;
    size_t o = ((size_t)(b * D_MODEL + c) * NM + m) * 2;
    qm[o] = qr; qm[o + 1] = qi;
}

// ---------------- K3: per-mode complex mixing; irfft scaling folded ----------
__global__ __launch_bounds__(64) void mix_kernel(const float* __restrict__ qm,
                                                 const float* __restrict__ wre,
                                                 const float* __restrict__ wim,
                                                 float* __restrict__ omB) {
    int o = blockIdx.x, h = blockIdx.y, m = threadIdx.x;
    float ar[NB], ai[NB];
#pragma unroll
    for (int b = 0; b < NB; ++b) { ar[b] = 0.f; ai[b] = 0.f; }
    for (int i = 0; i < NE; ++i) {
        size_t wo = (((size_t)(h * NE + i) * NE + o) * NM) + m;
        float wr = wre[wo], wi = wim[wo];
#pragma unroll
        for (int b = 0; b < NB; ++b) {
            float2 q = *(const float2*)(qm + ((size_t)(b * D_MODEL + h * NE + i) * NM + m) * 2);
            ar[b] = fmaf(q.x, wr, fmaf(-q.y, wi, ar[b]));
            ai[b] = fmaf(q.x, wi, fmaf(q.y, wr, ai[b]));
        }
    }
    float cm = (m == 0) ? (1.0f / T_LEN) : (2.0f / T_LEN);
    int cidx = h * NE + o;
#pragma unroll
    for (int b = 0; b < NB; ++b) {
        omB[((size_t)b * 128 + 2 * m) * D_MODEL + cidx]     = ar[b] * cm;
        omB[((size_t)b * 128 + 2 * m + 1) * D_MODEL + cidx] = (m == 0) ? 0.f : -ai[b] * cm;
    }
}

// ---------------- K4: x' = x + basis @ omB -> out (fp32) + xh hi/lo (bf16) ---
__global__ __launch_bounds__(256) void idft_kernel(const float* __restrict__ x,
                                                   const float* __restrict__ basis,
                                                   const float* __restrict__ omB,
                                                   ushort* __restrict__ xh_hi,
                                                   ushort* __restrict__ xh_lo,
                                                   float* __restrict__ out) {
    __shared__ float bs[64][129];
    __shared__ float os[128][65];
    int b = blockIdx.z;
    int tt = blockIdx.y * 64;
    int dd = blockIdx.x * 64;
    int tid = threadIdx.x;
    for (int i = tid; i < 64 * 128; i += 256) {
        int r = i >> 7, k = i & 127;
        bs[r][k] = basis[(size_t)(tt + r) * 128 + k];
    }
    for (int i = tid; i < 128 * 64; i += 256) {
        int k = i >> 6, dl = i & 63;
        os[k][dl] = omB[((size_t)b * 128 + k) * D_MODEL + dd + dl];
    }
    __syncthreads();
    int tx = tid & 15, ty = tid >> 4;
    int r0 = ty * 4, c0 = tx * 4;
    float acc[4][4] = {};
#pragma unroll 4
    for (int k = 0; k < 128; ++k) {
        float a[4], bv[4];
#pragma unroll
        for (int i = 0; i < 4; ++i) a[i] = bs[r0 + i][k];
#pragma unroll
        for (int j = 0; j < 4; ++j) bv[j] = os[k][c0 + j];
#pragma unroll
        for (int i = 0; i < 4; ++i)
#pragma unroll
            for (int j = 0; j < 4; ++j) acc[i][j] = fmaf(a[i], bv[j], acc[i][j]);
    }
#pragma unroll
    for (int i = 0; i < 4; ++i) {
        size_t off = ((size_t)b * T_LEN + tt + r0 + i) * D_MODEL + dd + c0;
        float4 xv = *(const float4*)(x + off);
        float4 o4;
        o4.x = xv.x + acc[i][0]; o4.y = xv.y + acc[i][1];
        o4.z = xv.z + acc[i][2]; o4.w = xv.w + acc[i][3];
        *(float4*)(out + off) = o4;
        ushort4 hv, lv;
        split_bf16(o4.x, hv.x, lv.x);
        split_bf16(o4.y, hv.y, lv.y);
        split_bf16(o4.z, hv.z, lv.z);
        split_bf16(o4.w, hv.w, lv.w);
        *(ushort4*)(xh_hi + off) = hv;
        *(ushort4*)(xh_lo + off) = lv;
    }
}

// ============== MFMA FFN: 128x128 tile, BK=32, 4 waves, 4x4 frags ============
// C[r][c] = sum_k A[r][k]*B[c][k]  (both operands K-major, split hi/lo bf16)
// 3-term split: Ah*Bh + Al*Bh + Ah*Bl  (Al*Bl ~ 2^-18, dropped)

// ---------------- K5: y1 = relu(x' @ W1^T) -> hi/lo bf16 ---------------------
__global__ __launch_bounds__(256) void ffn1_mfma(const ushort* __restrict__ Ag_h,
                                                 const ushort* __restrict__ Ag_l,
                                                 const ushort* __restrict__ Bg_h,
                                                 const ushort* __restrict__ Bg_l,
                                                 ushort* __restrict__ Yh,
                                                 ushort* __restrict__ Yl,
                                                 int co, int CH) {
    __shared__ ushort Ah[128][32], Al[128][32], Bh[128][32], Bl[128][32];
    int rr = blockIdx.y * 128;
    int ccl = blockIdx.x * 128;   // local col within chunk
    int cc = co + ccl;            // global col (row of W1)
    int tid = threadIdx.x;
    int lane = tid & 63, w = tid >> 6;
    int wr = (w >> 1) * 64, wc = (w & 1) * 64;
    f32x4 acc[4][4] = {};
    int c0 = w * 2;                      // this wave's 16-row chunk pair
    int srow = c0 * 16 + (lane >> 2);    // staging row (lane-linear)
    int koff = (lane & 3) * 8;           // staging k element offset

    for (int kk = 0; kk < D_MODEL; kk += 32) {
        GLOAD16(Ag_h + (size_t)(rr + srow) * D_MODEL + kk + koff, &Ah[c0 * 16][0]);
        GLOAD16(Ag_h + (size_t)(rr + srow + 16) * D_MODEL + kk + koff, &Ah[c0 * 16 + 16][0]);
        GLOAD16(Ag_l + (size_t)(rr + srow) * D_MODEL + kk + koff, &Al[c0 * 16][0]);
        GLOAD16(Ag_l + (size_t)(rr + srow + 16) * D_MODEL + kk + koff, &Al[c0 * 16 + 16][0]);
        GLOAD16(Bg_h + (size_t)(cc + srow) * D_MODEL + kk + koff, &Bh[c0 * 16][0]);
        GLOAD16(Bg_h + (size_t)(cc + srow + 16) * D_MODEL + kk + koff, &Bh[c0 * 16 + 16][0]);
        GLOAD16(Bg_l + (size_t)(cc + srow) * D_MODEL + kk + koff, &Bl[c0 * 16][0]);
        GLOAD16(Bg_l + (size_t)(cc + srow + 16) * D_MODEL + kk + koff, &Bl[c0 * 16 + 16][0]);
        __syncthreads();
        int arow = wr + (lane & 15);
        int kq = (lane >> 4) * 8;
        bf16x8 afh[4], afl[4];
#pragma unroll
        for (int i = 0; i < 4; ++i) {
            afh[i] = *(const bf16x8*)&Ah[arow + i * 16][kq];
            afl[i] = *(const bf16x8*)&Al[arow + i * 16][kq];
        }
#pragma unroll
        for (int j = 0; j < 4; ++j) {
            int brow = wc + j * 16 + (lane & 15);
            bf16x8 bfh = *(const bf16x8*)&Bh[brow][kq];
            bf16x8 bfl = *(const bf16x8*)&Bl[brow][kq];
#pragma unroll
            for (int i = 0; i < 4; ++i) {
                acc[i][j] = __builtin_amdgcn_mfma_f32_16x16x32_bf16(afh[i], bfh, acc[i][j], 0, 0, 0);
                acc[i][j] = __builtin_amdgcn_mfma_f32_16x16x32_bf16(afl[i], bfh, acc[i][j], 0, 0, 0);
                acc[i][j] = __builtin_amdgcn_mfma_f32_16x16x32_bf16(afh[i], bfl, acc[i][j], 0, 0, 0);
            }
        }
        __syncthreads();
    }
#pragma unroll
    for (int i = 0; i < 4; ++i) {
        int row = rr + wr + i * 16 + (lane >> 4) * 4;
#pragma unroll
        for (int j = 0; j < 4; ++j) {
            int col = ccl + wc + j * 16 + (lane & 15);
#pragma unroll
            for (int q = 0; q < 4; ++q) {
                float v = fmaxf(acc[i][j][q], 0.f);
                ushort h, l;
                split_bf16(v, h, l);
                size_t o = (size_t)(row + q) * CH + col;
                Yh[o] = h;
                Yl[o] = l;
            }
        }
    }
}

// ---------------- K6: out += y1 @ W2^T (K-chunk [co, co+CH)) -----------------
__global__ __launch_bounds__(256) void ffn2_mfma(const ushort* __restrict__ Ag_h,
                                                 const ushort* __restrict__ Ag_l,
                                                 const ushort* __restrict__ Bg_h,
                                                 const ushort* __restrict__ Bg_l,
                                                 float* __restrict__ out,
                                                 int co, int CH) {
    __shared__ ushort Ah[128][32], Al[128][32], Bh[128][32], Bl[128][32];
    int rr = blockIdx.y * 128;
    int dd = blockIdx.x * 128;
    int tid = threadIdx.x;
    int lane = tid & 63, w = tid >> 6;
    int wr = (w >> 1) * 64, wc = (w & 1) * 64;
    f32x4 acc[4][4] = {};
    int c0 = w * 2;
    int srow = c0 * 16 + (lane >> 2);
    int koff = (lane & 3) * 8;

    for (int kk = 0; kk < CH; kk += 32) {
        GLOAD16(Ag_h + (size_t)(rr + srow) * CH + kk + koff, &Ah[c0 * 16][0]);
        GLOAD16(Ag_h + (size_t)(rr + srow + 16) * CH + kk + koff, &Ah[c0 * 16 + 16][0]);
        GLOAD16(Ag_l + (size_t)(rr + srow) * CH + kk + koff, &Al[c0 * 16][0]);
        GLOAD16(Ag_l + (size_t)(rr + srow + 16) * CH + kk + koff, &Al[c0 * 16 + 16][0]);
        GLOAD16(Bg_h + (size_t)(dd + srow) * DFF + co + kk + koff, &Bh[c0 * 16][0]);
        GLOAD16(Bg_h + (size_t)(dd + srow + 16) * DFF + co + kk + koff, &Bh[c0 * 16 + 16][0]);
        GLOAD16(Bg_l + (size_t)(dd + srow) * DFF + co + kk + koff, &Bl[c0 * 16][0]);
        GLOAD16(Bg_l + (size_t)(dd + srow + 16) * DFF + co + kk + koff, &Bl[c0 * 16 + 16][0]);
        __syncthreads();
        int arow = wr + (lane & 15);
        int kq = (lane >> 4) * 8;
        bf16x8 afh[4], afl[4];
#pragma unroll
        for (int i = 0; i < 4; ++i) {
            afh[i] = *(const bf16x8*)&Ah[arow + i * 16][kq];
            afl[i] = *(const bf16x8*)&Al[arow + i * 16][kq];
        }
#pragma unroll
        for (int j = 0; j < 4; ++j) {
            int brow = wc + j * 16 + (lane & 15);
            bf16x8 bfh = *(const bf16x8*)&Bh[brow][kq];
            bf16x8 bfl = *(const bf16x8*)&Bl[brow][kq];
#pragma unroll
            for (int i = 0; i < 4; ++i) {
                acc[i][j] = __builtin_amdgcn_mfma_f32_16x16x32_bf16(afh[i], bfh, acc[i][j], 0, 0, 0);
                acc[i][j] = __builtin_amdgcn_mfma_f32_16x16x32_bf16(afl[i], bfh, acc[i][j], 0, 0, 0);
                acc[i][j] = __builtin_amdgcn_mfma_f32_16x16x32_bf16(afh[i], bfl, acc[i][j], 0, 0, 0);
            }
        }
        __syncthreads();
    }
#pragma unroll
    for (int i = 0; i < 4; ++i) {
        int row = rr + wr + i * 16 + (lane >> 4) * 4;
#pragma unroll
        for (int j = 0; j < 4; ++j) {
            int col = dd + wc + j * 16 + (lane & 15);
#pragma unroll
            for (int q = 0; q < 4; ++q) {
                size_t o = (size_t)(row + q) * D_MODEL + col;
                out[o] += acc[i][j][q];
            }
        }
    }
}

extern "C" void kernel_launch(void* const* d_in, const int* in_sizes, int n_in,
                              void* d_out, int out_size, void* d_ws, size_t ws_size,
                              hipStream_t stream) {
    const float* x   = (const float*)d_in[0];
    const float* Wp  = (const float*)d_in[1];
    const float* bpv = (const float*)d_in[2];
    const float* wre = (const float*)d_in[3];
    const float* wim = (const float*)d_in[4];
    const float* W1  = (const float*)d_in[5];
    const float* W2  = (const float*)d_in[6];
    float* out = (float*)d_out;

    char* ws = (char*)d_ws;
    const size_t MB = (size_t)1 << 20;
    float*  basis = (float*)(ws + 0 * MB);    // 2 MB
    float*  Xm    = (float*)(ws + 2 * MB);    // 2 MB
    float*  qm    = (float*)(ws + 4 * MB);    // 2 MB
    float*  omB   = (float*)(ws + 6 * MB);    // 2 MB
    ushort* w1h   = (ushort*)(ws + 8 * MB);   // 2 MB
    ushort* w1l   = (ushort*)(ws + 10 * MB);  // 2 MB
    ushort* w2h   = (ushort*)(ws + 12 * MB);  // 2 MB
    ushort* w2l   = (ushort*)(ws + 14 * MB);  // 2 MB
    ushort* xh_hi = (ushort*)(ws + 16 * MB);  // 32 MB
    ushort* xh_lo = (ushort*)(ws + 48 * MB);  // 32 MB
    char*   y1b   = ws + 80 * MB;             // y1 hi/lo chunk buffers
    // DFT partials: 16 MiB, lives in the xh_hi region (dead until idft runs).
    float*  pp    = (float*)(ws + 16 * MB);

    // largest FFN column chunk whose hi/lo y1 buffers fit the workspace
    size_t avail = (ws_size > 80 * MB) ? ws_size - 80 * MB : 0;
    int CH = 2048;
    while (CH > 128 && (size_t)NROWS * CH * 2 * sizeof(ushort) > avail) CH >>= 1;
    ushort* y1h = (ushort*)y1b;
    ushort* y1l = (ushort*)(y1b + (size_t)NROWS * CH * sizeof(ushort));

    basis_kernel<<<1024, 256, 0, stream>>>(basis);
    decomp_kernel<<<1024, 256, 0, stream>>>(W1, w1h, w1l, DFF * D_MODEL / 4);
    decomp_kernel<<<1024, 256, 0, stream>>>(W2, w2h, w2l, DFF * D_MODEL / 4);
    dft2_kernel<<<dim3(8, 8, TSPLIT), 256, 0, stream>>>(x, basis, pp);
    dft_reduce_kernel<<<(NB * D_MODEL * NK) / 256, 256, 0, stream>>>(pp, Xm);
    proj_kernel<<<dim3(64, 8), 512, 0, stream>>>(Xm, Wp, bpv, qm);
    mix_kernel<<<dim3(64, 8), 64, 0, stream>>>(qm, wre, wim, omB);
    idft_kernel<<<dim3(8, 64, 8), 256, 0, stream>>>(x, basis, omB, xh_hi, xh_lo, out);
    for (int co = 0; co < DFF; co += CH) {
        ffn1_mfma<<<dim3(CH / 128, NROWS / 128), 256, 0, stream>>>(
            xh_hi, xh_lo, w1h, w1l, y1h, y1l, co, CH);
        ffn2_mfma<<<dim3(D_MODEL / 128, NROWS / 128), 256, 0, stream>>>(
            y1h, y1l, w2h, w2l, out, co, CH);
    }
}

// Round 8
// 817.790 us; speedup vs baseline: 7.5951x; 1.0636x over previous
//
#include <hip/hip_runtime.h>
#include <hip/hip_bf16.h>

// FEDformer layer, MI355X. Round 7 kernel, second submission (round-7 bench
// never ran: GPU acquisition timeout).
//  - idft rewritten in the dft2-proven float4-microtile style (basisT staged)
//  - ffn1/ffn2: XCD-swizzled block mapping (T1) + BK=64 dual [128][32] buffers
//    (half the barriers, identical conflict-free tile layout)
//  - mix regridded to (o,h,b) for latency hiding; dft2 TSPLIT 8->16
// FFN on matrix cores via split-bf16 (hi/lo) 3-term GEMM (round-4/6, passed).
// B=8 T=4096 D=512 H=8 E=64 M=64 CM=4 (Dff=2048).

#define T_LEN 4096
#define D_MODEL 512
#define NB 8
#define NH 8
#define NE 64
#define NM 64
#define DFF 2048
#define NROWS (NB * T_LEN)  // 32768
#define NK 128              // 64 modes x (cos,sin)
#define TSPLIT 16
#define TCH (T_LEN / TSPLIT)  // 256

typedef __attribute__((ext_vector_type(8))) short bf16x8;
typedef __attribute__((ext_vector_type(4))) float f32x4;

__device__ inline ushort f2bf_rne(float f) {
    unsigned u = __float_as_uint(f);
    unsigned r = u + 0x7FFFu + ((u >> 16) & 1u);
    return (ushort)(r >> 16);
}
__device__ inline float bf2f(ushort h) { return __uint_as_float(((unsigned)h) << 16); }
__device__ inline void split_bf16(float v, ushort& h, ushort& l) {
    h = f2bf_rne(v);
    l = f2bf_rne(v - bf2f(h));
}

#define GLOAD16(gp, lp)                                                            \
    __builtin_amdgcn_global_load_lds(                                              \
        (const __attribute__((address_space(1))) void*)(gp),                       \
        (__attribute__((address_space(3))) void*)(lp), 16, 0, 0)

// -------- K0: basis[t][k] (k=2m cos, 2m+1 sin) AND basisT[k][t] --------------
__global__ __launch_bounds__(256) void basis_kernel(float* __restrict__ basis,
                                                    float* __restrict__ basisT) {
    int idx = blockIdx.x * 256 + threadIdx.x;  // 524288 = 128 k x 4096 t
    int k = idx >> 12, t = idx & 4095;
    int m = k >> 1;
    int r = (t * m) & (T_LEN - 1);
    float ang = (float)r * 1.5339807878856412e-3f;  // 2*pi/4096
    float s, c;
    sincosf(ang, &s, &c);
    float v = (k & 1) ? s : c;
    basisT[(size_t)k * T_LEN + t] = v;      // coalesced
    basis[(size_t)t * NK + k]    = v;       // scattered (2 MB, once per call)
}

// ---------------- K0b: fp32 -> (hi,lo) bf16 decomposition --------------------
__global__ __launch_bounds__(256) void decomp_kernel(const float* __restrict__ in,
                                                     ushort* __restrict__ hi,
                                                     ushort* __restrict__ lo, int n4) {
    int i = blockIdx.x * 256 + threadIdx.x;
    if (i >= n4) return;
    float4 v = ((const float4*)in)[i];
    ushort4 h, l;
    split_bf16(v.x, h.x, l.x);
    split_bf16(v.y, h.y, l.y);
    split_bf16(v.z, h.z, l.z);
    split_bf16(v.w, h.w, l.w);
    ((ushort4*)hi)[i] = h;
    ((ushort4*)lo)[i] = l;
}

// ---------------- K1: DFT as tiled GEMM: pp[tc][b][d][k] partial sums --------
__global__ __launch_bounds__(256) void dft2_kernel(const float* __restrict__ x,
                                                   const float* __restrict__ basis,
                                                   float* __restrict__ pp) {
    __shared__ float xs[64][68];   // [t][d] +4 pad
    __shared__ float bs[64][132];  // [t][k] +4 pad
    int d0 = blockIdx.x * 64;
    int b  = blockIdx.y;
    int tc = blockIdx.z;
    int t0 = tc * TCH;
    int tid = threadIdx.x;
    int tx = tid & 15, ty = tid >> 4;
    float4 acc0[4] = {};
    float4 acc1[4] = {};

    for (int tt = 0; tt < TCH; tt += 64) {
        const float* xrow = x + ((size_t)b * T_LEN + t0 + tt) * D_MODEL + d0;
#pragma unroll
        for (int l = 0; l < 4; ++l) {
            int f = (tid + l * 256) * 4;
            int r = f >> 6, c = f & 63;
            *(float4*)&xs[r][c] = *(const float4*)(xrow + (size_t)r * D_MODEL + c);
        }
        const float* brow = basis + (size_t)(t0 + tt) * NK;
#pragma unroll
        for (int l = 0; l < 8; ++l) {
            int f = (tid + l * 256) * 4;
            int r = f >> 7, c = f & 127;
            *(float4*)&bs[r][c] = *(const float4*)(brow + (size_t)r * NK + c);
        }
        __syncthreads();
#pragma unroll 4
        for (int t = 0; t < 64; ++t) {
            float4 xv = *(const float4*)&xs[t][ty * 4];
            float4 b0 = *(const float4*)&bs[t][tx * 4];
            float4 b1 = *(const float4*)&bs[t][tx * 4 + 64];
            float xa[4] = {xv.x, xv.y, xv.z, xv.w};
#pragma unroll
            for (int di = 0; di < 4; ++di) {
                acc0[di].x = fmaf(xa[di], b0.x, acc0[di].x);
                acc0[di].y = fmaf(xa[di], b0.y, acc0[di].y);
                acc0[di].z = fmaf(xa[di], b0.z, acc0[di].z);
                acc0[di].w = fmaf(xa[di], b0.w, acc0[di].w);
                acc1[di].x = fmaf(xa[di], b1.x, acc1[di].x);
                acc1[di].y = fmaf(xa[di], b1.y, acc1[di].y);
                acc1[di].z = fmaf(xa[di], b1.z, acc1[di].z);
                acc1[di].w = fmaf(xa[di], b1.w, acc1[di].w);
            }
        }
        __syncthreads();
    }
#pragma unroll
    for (int di = 0; di < 4; ++di) {
        int d = d0 + ty * 4 + di;
        size_t base = (((size_t)tc * NB + b) * D_MODEL + d) * NK;
        *(float4*)(pp + base + tx * 4)      = acc0[di];
        *(float4*)(pp + base + 64 + tx * 4) = acc1[di];
    }
}

// ---------------- K1b: reduce t-chunks, apply -sin sign ----------------------
__global__ __launch_bounds__(256) void dft_reduce_kernel(const float* __restrict__ pp,
                                                         float* __restrict__ Xm) {
    int idx = blockIdx.x * 256 + threadIdx.x;  // 524288
    const size_t stride = (size_t)NB * D_MODEL * NK;
    float s = 0.f;
#pragma unroll
    for (int tc = 0; tc < TSPLIT; ++tc) s += pp[(size_t)tc * stride + idx];
    Xm[idx] = (idx & 1) ? -s : s;
}

// ---------------- K2: qm[b][c][m][2] = sum_d Xm[b][d][m] * Wp[d][c] ----------
__global__ __launch_bounds__(512) void proj_kernel(const float* __restrict__ Xm,
                                                   const float* __restrict__ Wp,
                                                   const float* __restrict__ bpv,
                                                   float* __restrict__ qm) {
    int m = blockIdx.x, b = blockIdx.y;
    int c = threadIdx.x;
    float qr = 0.f, qi = 0.f;
#pragma unroll 4
    for (int d = 0; d < D_MODEL; ++d) {
        float2 xv = *(const float2*)(Xm + ((size_t)(b * D_MODEL + d) * NM + m) * 2);
        float w = Wp[(size_t)d * D_MODEL + c];
        qr = fmaf(xv.x, w, qr);
        qi = fmaf(xv.y, w, qi);
    }
    if (m == 0) qr += bpv[c] * (float)T_LEN;
    size_t o = ((size_t)(b * D_MODEL + c) * NM + m) * 2;
    qm[o] = qr; qm[o + 1] = qi;
}

// ---------------- K3: per-mode complex mixing; irfft scaling folded ----------
// regrid: one wave per (o,h,b) -> 4096 waves (16/CU) for latency hiding.
__global__ __launch_bounds__(64) void mix_kernel(const float* __restrict__ qm,
                                                 const float* __restrict__ wre,
                                                 const float* __restrict__ wim,
                                                 float* __restrict__ omB) {
    int o = blockIdx.x, h = blockIdx.y, b = blockIdx.z, m = threadIdx.x;
    float ar = 0.f, ai = 0.f;
    for (int i = 0; i < NE; ++i) {
        size_t wo = (((size_t)(h * NE + i) * NE + o) * NM) + m;
        float wr = wre[wo], wi = wim[wo];
        float2 q = *(const float2*)(qm + ((size_t)(b * D_MODEL + h * NE + i) * NM + m) * 2);
        ar = fmaf(q.x, wr, fmaf(-q.y, wi, ar));
        ai = fmaf(q.x, wi, fmaf(q.y, wr, ai));
    }
    float cm = (m == 0) ? (1.0f / T_LEN) : (2.0f / T_LEN);
    int cidx = h * NE + o;
    omB[((size_t)b * 128 + 2 * m) * D_MODEL + cidx]     = ar * cm;
    omB[((size_t)b * 128 + 2 * m + 1) * D_MODEL + cidx] = (m == 0) ? 0.f : -ai * cm;
}

// -------- K4: idft as dft2-style microtile: x' = x + basisT^T @ omB ----------
// out tile [64 t][64 d]; K = 128 coeffs in LDS rows; float4 reads both operands.
__global__ __launch_bounds__(256) void idft2_kernel(const float* __restrict__ x,
                                                    const float* __restrict__ basisT,
                                                    const float* __restrict__ omB,
                                                    ushort* __restrict__ xh_hi,
                                                    ushort* __restrict__ xh_lo,
                                                    float* __restrict__ out) {
    __shared__ float bT[128][68];  // [k][t] +4 pad
    __shared__ float os[128][68];  // [k][d] +4 pad
    int dd = blockIdx.x * 64;
    int tt = blockIdx.y * 64;
    int b  = blockIdx.z;
    int tid = threadIdx.x;
#pragma unroll
    for (int l = 0; l < 8; ++l) {
        int f = (tid + l * 256) * 4;
        int r = f >> 6, c = f & 63;
        *(float4*)&bT[r][c] = *(const float4*)(basisT + (size_t)r * T_LEN + tt + c);
        *(float4*)&os[r][c] = *(const float4*)(omB + ((size_t)b * NK + r) * D_MODEL + dd + c);
    }
    __syncthreads();
    int tx = tid & 15, ty = tid >> 4;  // tx -> d, ty -> t
    float4 acc[4] = {};                // acc[i] = float4 over d, t-row i
#pragma unroll 4
    for (int k = 0; k < 128; ++k) {
        float4 av = *(const float4*)&bT[k][ty * 4];
        float4 bv = *(const float4*)&os[k][tx * 4];
        float aa[4] = {av.x, av.y, av.z, av.w};
#pragma unroll
        for (int i = 0; i < 4; ++i) {
            acc[i].x = fmaf(aa[i], bv.x, acc[i].x);
            acc[i].y = fmaf(aa[i], bv.y, acc[i].y);
            acc[i].z = fmaf(aa[i], bv.z, acc[i].z);
            acc[i].w = fmaf(aa[i], bv.w, acc[i].w);
        }
    }
#pragma unroll
    for (int i = 0; i < 4; ++i) {
        size_t off = ((size_t)b * T_LEN + tt + ty * 4 + i) * D_MODEL + dd + tx * 4;
        float4 xv = *(const float4*)(x + off);
        float4 o4;
        o4.x = xv.x + acc[i].x; o4.y = xv.y + acc[i].y;
        o4.z = xv.z + acc[i].z; o4.w = xv.w + acc[i].w;
        *(float4*)(out + off) = o4;
        ushort4 hv, lv;
        split_bf16(o4.x, hv.x, lv.x);
        split_bf16(o4.y, hv.y, lv.y);
        split_bf16(o4.z, hv.z, lv.z);
        split_bf16(o4.w, hv.w, lv.w);
        *(ushort4*)(xh_hi + off) = hv;
        *(ushort4*)(xh_lo + off) = lv;
    }
}

// ============== MFMA FFN: 128x128 tile, BK=64 (2x32 buffers), 4 waves ========
// 3-term split: Ah*Bh + Al*Bh + Ah*Bl.  XCD-swizzled 1-D grid (T1).

// ---------------- K5: y1 = relu(x' @ W1^T) -> hi/lo bf16 ---------------------
__global__ __launch_bounds__(256) void ffn1_mfma(const ushort* __restrict__ Ag_h,
                                                 const ushort* __restrict__ Ag_l,
                                                 const ushort* __restrict__ Bg_h,
                                                 const ushort* __restrict__ Bg_l,
                                                 ushort* __restrict__ Yh,
                                                 ushort* __restrict__ Yl,
                                                 int co, int CH, int nx) {
    __shared__ ushort Ah[2][128][32], Al[2][128][32], Bh[2][128][32], Bl[2][128][32];
    // XCD-aware bijective swizzle: nwg % 8 == 0 (nwg = nx*256)
    int nwg = gridDim.x;
    int per = nwg >> 3;
    int lin = (blockIdx.x & 7) * per + (blockIdx.x >> 3);
    int bx = lin % nx, by = lin / nx;
    int rr = by * 128;
    int ccl = bx * 128;
    int cc = co + ccl;
    int tid = threadIdx.x;
    int lane = tid & 63, w = tid >> 6;
    int wr = (w >> 1) * 64, wc = (w & 1) * 64;
    f32x4 acc[4][4] = {};
    int c0 = w * 2;
    int srow = c0 * 16 + (lane >> 2);
    int koff = (lane & 3) * 8;

    for (int kk = 0; kk < D_MODEL; kk += 64) {
#pragma unroll
        for (int h = 0; h < 2; ++h) {
            int kg = kk + h * 32;
            GLOAD16(Ag_h + (size_t)(rr + srow) * D_MODEL + kg + koff, &Ah[h][c0 * 16][0]);
            GLOAD16(Ag_h + (size_t)(rr + srow + 16) * D_MODEL + kg + koff, &Ah[h][c0 * 16 + 16][0]);
            GLOAD16(Ag_l + (size_t)(rr + srow) * D_MODEL + kg + koff, &Al[h][c0 * 16][0]);
            GLOAD16(Ag_l + (size_t)(rr + srow + 16) * D_MODEL + kg + koff, &Al[h][c0 * 16 + 16][0]);
            GLOAD16(Bg_h + (size_t)(cc + srow) * D_MODEL + kg + koff, &Bh[h][c0 * 16][0]);
            GLOAD16(Bg_h + (size_t)(cc + srow + 16) * D_MODEL + kg + koff, &Bh[h][c0 * 16 + 16][0]);
            GLOAD16(Bg_l + (size_t)(cc + srow) * D_MODEL + kg + koff, &Bl[h][c0 * 16][0]);
            GLOAD16(Bg_l + (size_t)(cc + srow + 16) * D_MODEL + kg + koff, &Bl[h][c0 * 16 + 16][0]);
        }
        __syncthreads();
        int arow = wr + (lane & 15);
        int kq = (lane >> 4) * 8;
#pragma unroll
        for (int h = 0; h < 2; ++h) {
            bf16x8 afh[4], afl[4];
#pragma unroll
            for (int i = 0; i < 4; ++i) {
                afh[i] = *(const bf16x8*)&Ah[h][arow + i * 16][kq];
                afl[i] = *(const bf16x8*)&Al[h][arow + i * 16][kq];
            }
#pragma unroll
            for (int j = 0; j < 4; ++j) {
                int brow = wc + j * 16 + (lane & 15);
                bf16x8 bfh = *(const bf16x8*)&Bh[h][brow][kq];
                bf16x8 bfl = *(const bf16x8*)&Bl[h][brow][kq];
#pragma unroll
                for (int i = 0; i < 4; ++i) {
                    acc[i][j] = __builtin_amdgcn_mfma_f32_16x16x32_bf16(afh[i], bfh, acc[i][j], 0, 0, 0);
                    acc[i][j] = __builtin_amdgcn_mfma_f32_16x16x32_bf16(afl[i], bfh, acc[i][j], 0, 0, 0);
                    acc[i][j] = __builtin_amdgcn_mfma_f32_16x16x32_bf16(afh[i], bfl, acc[i][j], 0, 0, 0);
                }
            }
        }
        __syncthreads();
    }
#pragma unroll
    for (int i = 0; i < 4; ++i) {
        int row = rr + wr + i * 16 + (lane >> 4) * 4;
#pragma unroll
        for (int j = 0; j < 4; ++j) {
            int col = ccl + wc + j * 16 + (lane & 15);
#pragma unroll
            for (int q = 0; q < 4; ++q) {
                float v = fmaxf(acc[i][j][q], 0.f);
                ushort h, l;
                split_bf16(v, h, l);
                size_t o = (size_t)(row + q) * CH + col;
                Yh[o] = h;
                Yl[o] = l;
            }
        }
    }
}

// ---------------- K6: out += y1 @ W2^T (K-chunk [co, co+CH)) -----------------
__global__ __launch_bounds__(256) void ffn2_mfma(const ushort* __restrict__ Ag_h,
                                                 const ushort* __restrict__ Ag_l,
                                                 const ushort* __restrict__ Bg_h,
                                                 const ushort* __restrict__ Bg_l,
                                                 float* __restrict__ out,
                                                 int co, int CH) {
    __shared__ ushort Ah[2][128][32], Al[2][128][32], Bh[2][128][32], Bl[2][128][32];
    int nwg = gridDim.x;  // 1024
    int per = nwg >> 3;
    int lin = (blockIdx.x & 7) * per + (blockIdx.x >> 3);
    int bx = lin & 3, by = lin >> 2;
    int rr = by * 128;
    int dd = bx * 128;
    int tid = threadIdx.x;
    int lane = tid & 63, w = tid >> 6;
    int wr = (w >> 1) * 64, wc = (w & 1) * 64;
    f32x4 acc[4][4] = {};
    int c0 = w * 2;
    int srow = c0 * 16 + (lane >> 2);
    int koff = (lane & 3) * 8;

    for (int kk = 0; kk < CH; kk += 64) {
#pragma unroll
        for (int h = 0; h < 2; ++h) {
            int kg = kk + h * 32;
            GLOAD16(Ag_h + (size_t)(rr + srow) * CH + kg + koff, &Ah[h][c0 * 16][0]);
            GLOAD16(Ag_h + (size_t)(rr + srow + 16) * CH + kg + koff, &Ah[h][c0 * 16 + 16][0]);
            GLOAD16(Ag_l + (size_t)(rr + srow) * CH + kg + koff, &Al[h][c0 * 16][0]);
            GLOAD16(Ag_l + (size_t)(rr + srow + 16) * CH + kg + koff, &Al[h][c0 * 16 + 16][0]);
            GLOAD16(Bg_h + (size_t)(dd + srow) * DFF + co + kg + koff, &Bh[h][c0 * 16][0]);
            GLOAD16(Bg_h + (size_t)(dd + srow + 16) * DFF + co + kg + koff, &Bh[h][c0 * 16 + 16][0]);
            GLOAD16(Bg_l + (size_t)(dd + srow) * DFF + co + kg + koff, &Bl[h][c0 * 16][0]);
            GLOAD16(Bg_l + (size_t)(dd + srow + 16) * DFF + co + kg + koff, &Bl[h][c0 * 16 + 16][0]);
        }
        __syncthreads();
        int arow = wr + (lane & 15);
        int kq = (lane >> 4) * 8;
#pragma unroll
        for (int h = 0; h < 2; ++h) {
            bf16x8 afh[4], afl[4];
#pragma unroll
            for (int i = 0; i < 4; ++i) {
                afh[i] = *(const bf16x8*)&Ah[h][arow + i * 16][kq];
                afl[i] = *(const bf16x8*)&Al[h][arow + i * 16][kq];
            }
#pragma unroll
            for (int j = 0; j < 4; ++j) {
                int brow = wc + j * 16 + (lane & 15);
                bf16x8 bfh = *(const bf16x8*)&Bh[h][brow][kq];
                bf16x8 bfl = *(const bf16x8*)&Bl[h][brow][kq];
#pragma unroll
                for (int i = 0; i < 4; ++i) {
                    acc[i][j] = __builtin_amdgcn_mfma_f32_16x16x32_bf16(afh[i], bfh, acc[i][j], 0, 0, 0);
                    acc[i][j] = __builtin_amdgcn_mfma_f32_16x16x32_bf16(afl[i], bfh, acc[i][j], 0, 0, 0);
                    acc[i][j] = __builtin_amdgcn_mfma_f32_16x16x32_bf16(afh[i], bfl, acc[i][j], 0, 0, 0);
                }
            }
        }
        __syncthreads();
    }
#pragma unroll
    for (int i = 0; i < 4; ++i) {
        int row = rr + wr + i * 16 + (lane >> 4) * 4;
#pragma unroll
        for (int j = 0; j < 4; ++j) {
            int col = dd + wc + j * 16 + (lane & 15);
#pragma unroll
            for (int q = 0; q < 4; ++q) {
                size_t o = (size_t)(row + q) * D_MODEL + col;
                out[o] += acc[i][j][q];
            }
        }
    }
}

extern "C" void kernel_launch(void* const* d_in, const int* in_sizes, int n_in,
                              void* d_out, int out_size, void* d_ws, size_t ws_size,
                              hipStream_t stream) {
    const float* x   = (const float*)d_in[0];
    const float* Wp  = (const float*)d_in[1];
    const float* bpv = (const float*)d_in[2];
    const float* wre = (const float*)d_in[3];
    const float* wim = (const float*)d_in[4];
    const float* W1  = (const float*)d_in[5];
    const float* W2  = (const float*)d_in[6];
    float* out = (float*)d_out;

    char* ws = (char*)d_ws;
    const size_t MB = (size_t)1 << 20;
    float*  basis  = (float*)(ws + 0 * MB);    // 2 MB  [t][k]
    float*  Xm     = (float*)(ws + 2 * MB);    // 2 MB
    float*  qm     = (float*)(ws + 4 * MB);    // 2 MB
    float*  omB    = (float*)(ws + 6 * MB);    // 2 MB
    ushort* w1h    = (ushort*)(ws + 8 * MB);   // 2 MB
    ushort* w1l    = (ushort*)(ws + 10 * MB);  // 2 MB
    ushort* w2h    = (ushort*)(ws + 12 * MB);  // 2 MB
    ushort* w2l    = (ushort*)(ws + 14 * MB);  // 2 MB
    ushort* xh_hi  = (ushort*)(ws + 16 * MB);  // 32 MB
    ushort* xh_lo  = (ushort*)(ws + 48 * MB);  // 32 MB
    float*  basisT = (float*)(ws + 80 * MB);   // 2 MB  [k][t]
    char*   y1b    = ws + 82 * MB;             // y1 hi/lo chunk buffers
    // DFT partials: 32 MiB, alias xh_hi region (dead until idft2 runs).
    float*  pp     = (float*)(ws + 16 * MB);

    // largest FFN column chunk whose hi/lo y1 buffers fit the workspace
    size_t avail = (ws_size > 82 * MB) ? ws_size - 82 * MB : 0;
    int CH = 2048;
    while (CH > 128 && (size_t)NROWS * CH * 2 * sizeof(ushort) > avail) CH >>= 1;
    ushort* y1h = (ushort*)y1b;
    ushort* y1l = (ushort*)(y1b + (size_t)NROWS * CH * sizeof(ushort));

    basis_kernel<<<2048, 256, 0, stream>>>(basis, basisT);
    decomp_kernel<<<1024, 256, 0, stream>>>(W1, w1h, w1l, DFF * D_MODEL / 4);
    decomp_kernel<<<1024, 256, 0, stream>>>(W2, w2h, w2l, DFF * D_MODEL / 4);
    dft2_kernel<<<dim3(8, 8, TSPLIT), 256, 0, stream>>>(x, basis, pp);
    dft_reduce_kernel<<<(NB * D_MODEL * NK) / 256, 256, 0, stream>>>(pp, Xm);
    proj_kernel<<<dim3(64, 8), 512, 0, stream>>>(Xm, Wp, bpv, qm);
    mix_kernel<<<dim3(64, 8, 8), 64, 0, stream>>>(qm, wre, wim, omB);
    idft2_kernel<<<dim3(8, 64, 8), 256, 0, stream>>>(x, basisT, omB, xh_hi, xh_lo, out);
    for (int co = 0; co < DFF; co += CH) {
        int nx = CH / 128;
        ffn1_mfma<<<nx * 256, 256, 0, stream>>>(
            xh_hi, xh_lo, w1h, w1l, y1h, y1l, co, CH, nx);
        ffn2_mfma<<<1024, 256, 0, stream>>>(
            y1h, y1l, w2h, w2l, out, co, CH);
    }
}